// Round 1
// 16948.546 us; speedup vs baseline: 2.1423x; 2.1423x over previous
//
#include <hip/hip_runtime.h>
#include <stdint.h>

// Problem dims
#define TD   1000
#define BB   64
#define HH   1024
#define EE   512
#define MMEL 80
#define TMEL 2000
#define RTOT (TD*BB)   // 64000 rows, row index = t*64 + b
#define BH   (BB*HH)   // 65536 elements per time-slot
#define DRNG 64        // d2 ring depth (steps)

typedef __attribute__((ext_vector_type(8))) short short8;   // 8 bf16 (4 VGPRs)
typedef __attribute__((ext_vector_type(4))) float f32x4;

__device__ __forceinline__ float bf2f(uint16_t h){ return __uint_as_float(((uint32_t)h)<<16); }
__device__ __forceinline__ uint16_t f2bf(float f){
  uint32_t u = __float_as_uint(f);
  return (uint16_t)((u + 0x7fffu + ((u>>16)&1u)) >> 16);   // RTNE
}

__device__ __forceinline__ void async16(const void* g, void* l) {
  __builtin_amdgcn_global_load_lds((const __attribute__((address_space(1))) void*)g,
                                   (__attribute__((address_space(3))) void*)l, 16, 0, 0);
}

__device__ __forceinline__ f32x4 mfma16(short8 a, short8 b, f32x4 c){
  return __builtin_amdgcn_mfma_f32_16x16x32_bf16(a, b, c, 0, 0, 0);
}

// ---------------- small prep kernels ----------------

__global__ void k_zero16(uint16_t* p, int n){ int i=blockIdx.x*256+threadIdx.x; if(i<n) p[i]=0; }
__global__ void k_zero32(unsigned* p, int n){ int i=blockIdx.x*256+threadIdx.x; if(i<n) p[i]=0u; }
__global__ void k_fill(float* p, int n, float v){ int i=blockIdx.x*256+threadIdx.x; if(i<n) p[i]=v; }

// f32 -> bf16 slice/pad copy. dst[r, c] = (c<cols)? src[r*src_ld + col0 + c] : 0
__global__ void k_cast(const float* __restrict__ src, uint16_t* __restrict__ dst,
                       int rows, int src_ld, int col0, int cols, int dst_ld){
  int i = blockIdx.x*256 + threadIdx.x;
  if (i >= rows*dst_ld) return;
  int r = i/dst_ld, c = i - r*dst_ld;
  float v = (c < cols) ? src[(size_t)r*src_ld + col0 + c] : 0.f;
  dst[i] = f2bf(v);
}

// teacher-forced decoder inputs, padded K=96: row t*64+b, di[t]= t==0?0:dec[b, 2t-1, :]
__global__ void k_di(const float* __restrict__ dec, uint16_t* __restrict__ di){
  int i = blockIdx.x*256 + threadIdx.x;
  if (i >= RTOT*96) return;
  int row = i/96, c = i - row*96;
  int t = row>>6, b = row&63;
  float v = 0.f;
  if (c < MMEL && t > 0) v = dec[((size_t)b*TMEL + (2*t-1))*MMEL + c];
  di[i] = f2bf(v);
}

// pooled memory: MEM[t*64+b, e] = 0.5*(memorys[b,2t,e]+memorys[b,2t+1,e])
__global__ void k_mem(const float* __restrict__ mem, uint16_t* __restrict__ out){
  int i = blockIdx.x*256 + threadIdx.x;
  if (i >= RTOT*EE) return;
  int row = i/EE, e = i - row*EE;
  int t = row>>6, b = row&63;
  size_t base = ((size_t)b*TMEL + 2*t)*EE + e;
  out[i] = f2bf(0.5f*(mem[base] + mem[base+EE]));
}

// ---------------- tiled bf16 MFMA GEMM (batched pre/post passes) ----------------
// C[M,N] = [A1 | A2][M, K1+K2] @ B[N,K]^T (+bias)(+Dadd)(relu?)
// M = 64000 (500 full 128-tiles, blockIdx.y). OM: 0 bf16 linear, 1 f32 remap (b,t), 2 f32 linear.
// DT: Dadd dtype 0 bf16, 1 f32.

template<int OM, int DT>
__global__ __launch_bounds__(256)
void k_gemm(const uint16_t* __restrict__ A1p, int K1, int lda1,
            const uint16_t* __restrict__ A2p, int K2, int lda2,
            const uint16_t* __restrict__ Bw, int ldb,
            void* __restrict__ Cp, int ldc,
            const float* __restrict__ bias,
            const void* __restrict__ Dadd, int ldd,
            int N, int relu)
{
  __shared__ __align__(16) uint16_t As[128*32];
  __shared__ __align__(16) uint16_t Bs[128*32];
  const int tid = threadIdx.x;
  const int w = tid>>6, lane = tid&63;
  const int q = lane>>4, ln = lane&15;
  const int m0 = blockIdx.y*128, n0 = blockIdx.x*128;
  const int wr = (w&1)*64, wc = (w>>1)*64;
  const int srow = w*32 + (lane>>2);
  const int scol = (lane&3)*8;
  const uint16_t* A1g = A1p + (size_t)(m0+srow)*lda1 + scol;
  const uint16_t* A1g2 = A1g + (size_t)16*lda1;
  const uint16_t* A2g = A2p ? A2p + (size_t)(m0+srow)*lda2 + scol : nullptr;
  const uint16_t* A2g2 = A2p ? A2g + (size_t)16*lda2 : nullptr;
  int bn1 = n0+srow;     bn1 = bn1 < N ? bn1 : N-1;
  int bn2 = n0+srow+16;  bn2 = bn2 < N ? bn2 : N-1;
  const uint16_t* Bg  = Bw + (size_t)bn1*ldb + scol;
  const uint16_t* Bg2 = Bw + (size_t)bn2*ldb + scol;
  uint16_t* As0 = &As[(w*32)*32];
  uint16_t* As1 = &As[(w*32+16)*32];
  uint16_t* Bs0 = &Bs[(w*32)*32];
  uint16_t* Bs1 = &Bs[(w*32+16)*32];
  const int K = K1 + K2;

  f32x4 acc[4][4] = {};
  for (int kt=0; kt<K; kt+=32) {
    __syncthreads();
    if (kt < K1) { async16(A1g+kt, As0);  async16(A1g2+kt, As1); }
    else         { async16(A2g+(kt-K1), As0);  async16(A2g2+(kt-K1), As1); }
    async16(Bg+kt, Bs0);  async16(Bg2+kt, Bs1);
    __syncthreads();
    short8 af[4], bfr[4];
    #pragma unroll
    for (int i=0;i<4;++i) af[i]  = *(const short8*)&As[(wr+16*i+ln)*32 + q*8];
    #pragma unroll
    for (int j=0;j<4;++j) bfr[j] = *(const short8*)&Bs[(wc+16*j+ln)*32 + q*8];
    #pragma unroll
    for (int i=0;i<4;++i)
      #pragma unroll
      for (int j=0;j<4;++j)
        acc[i][j] = mfma16(af[i], bfr[j], acc[i][j]);
  }

  #pragma unroll
  for (int i=0;i<4;++i){
    #pragma unroll
    for (int j=0;j<4;++j){
      int col = n0 + wc + 16*j + ln;
      if (col >= N) continue;
      float bv = bias ? bias[col] : 0.f;
      #pragma unroll
      for (int r=0;r<4;++r){
        int row = m0 + wr + 16*i + 4*q + r;
        float v = acc[i][j][r] + bv;
        if (Dadd) {
          if (DT) v += ((const float*)Dadd)[(size_t)row*ldd + col];
          else    v += bf2f(((const uint16_t*)Dadd)[(size_t)row*ldd + col]);
        }
        if (relu) v = v > 0.f ? v : 0.f;
        if (OM==0) {
          ((uint16_t*)Cp)[(size_t)row*ldc + col] = f2bf(v);
        } else if (OM==1) {
          int t = row>>6, b = row&63;
          ((float*)Cp)[((size_t)b*TD + t)*ldc + col] = v;
        } else {
          ((float*)Cp)[(size_t)row*ldc + col] = v;
        }
      }
    }
  }
}

// ---------------- distributed flag signal/wait ----------------
// Producer: __syncthreads() (each wave drains vmcnt before barrier), then thread 0
// release-stores its generation flag (own 128B line). Consumer: lanes poll one flag
// each; acquire fence AFTER observation so stale L1/L2 lines cannot be refilled.

__device__ __forceinline__ void signal_flag(unsigned* f, int idx, unsigned v){
  if (threadIdx.x == 0)
    __hip_atomic_store(f + idx*32, v, __ATOMIC_RELEASE, __HIP_MEMORY_SCOPE_AGENT);
}
__device__ __forceinline__ void wait_flags(unsigned* f, int n, unsigned target){
  if ((int)threadIdx.x < n) {
    unsigned* p = f + threadIdx.x*32;
    while (__hip_atomic_load(p, __ATOMIC_RELAXED, __HIP_MEMORY_SCOPE_AGENT) < target)
      __builtin_amdgcn_s_sleep(1);
    __builtin_amdgcn_fence(__ATOMIC_ACQUIRE, "agent");
  }
  __syncthreads();
}

// ---------------- per-step input-side matmul (row-split, weights in LDS) ----------------
// wave w owns batch rows 16w..16w+15, full K. smw holds [48][LDK] (or [32][1024]) slice,
// XOR-swizzled: u16 idx ^= (row&7)<<3 (16B granularity) -> conflict-free ds_read_b128.
// C layout: ga[g][r] is (row = 16w+4q+r, col = j = i*16+ln) -- matches elementwise mapping.

template<int ROLE>
__device__ __forceinline__ void fetch_gi(int t,
    const uint16_t* X2, const uint16_t* MEM, const uint16_t* gsrc,
    const uint16_t* smw, int w, int q, int ln, f32x4 (&ga)[3])
{
  ga[0] = (f32x4){0.f,0.f,0.f,0.f}; ga[1] = ga[0]; ga[2] = ga[0];
  const int swz = (ln&7)<<3;
  if (ROLE == 1) {
    // gi1 = [x2 | mem] @ W1ih^T   (K = 256 + 512)
    const uint16_t* a0 = X2 + ((size_t)t*64 + 16*w + ln)*256 + q*8;
    #pragma unroll 4
    for (int ks=0; ks<8; ++ks) {
      short8 a = *(const short8*)(a0 + ks*32);
      #pragma unroll
      for (int g=0; g<3; ++g) {
        short8 b = *(const short8*)(smw + ((((g*16+ln)*768) + ks*32 + q*8) ^ swz));
        ga[g] = mfma16(a, b, ga[g]);
      }
    }
    const uint16_t* a1 = MEM + ((size_t)t*64 + 16*w + ln)*512 + q*8;
    #pragma unroll 4
    for (int ks=0; ks<16; ++ks) {
      short8 a = *(const short8*)(a1 + ks*32);
      #pragma unroll
      for (int g=0; g<3; ++g) {
        short8 b = *(const short8*)(smw + ((((g*16+ln)*768) + 256 + ks*32 + q*8) ^ swz));
        ga[g] = mfma16(a, b, ga[g]);
      }
    }
  } else {
    // gi2 = d2[t] @ W2ih^T  (ring slot) / gi3 = r2[t] @ W3ih^T  (full seq), K = 1024
    const uint16_t* base = gsrc + (ROLE==2 ? (size_t)(t % DRNG)*BH : (size_t)t*BH);
    const uint16_t* a0 = base + (size_t)(16*w + ln)*1024 + q*8;
    #pragma unroll 8
    for (int ks=0; ks<32; ++ks) {
      short8 a = *(const short8*)(a0 + ks*32);
      #pragma unroll
      for (int g=0; g<3; ++g) {
        short8 b = *(const short8*)(smw + ((((g*16+ln)*1024) + ks*32 + q*8) ^ swz));
        ga[g] = mfma16(a, b, ga[g]);
      }
    }
  }
}

// ---------------- recurrent role (L1 / L2 / L3) ----------------
// 64 blocks per role; block owns 16 h-columns (j = i*16 + ln) for all 64 batches.
// whh slice (3x16x1024) in registers, K-split across the 4 waves + LDS reduce.
// Input-side gi matmul is prefetched into the round TAIL (off the recurrent
// critical path). ROLE!=1 also writes rout[t] = h_new + gsrc[t] (r2 / r3).

template<int ROLE>
__device__ void rec_role(int i,
    const uint16_t* whh, const uint16_t* wih,
    const float* bih, const float* bhh,
    const uint16_t* X2, const uint16_t* MEM, const uint16_t* gsrc,
    uint16_t* Hs, uint16_t* rout,
    unsigned* fOwn, unsigned* fDep, int nDep,
    uint16_t* smw, float* red)
{
  const int tid = threadIdx.x;
  const int w = tid>>6, lane = tid&63;
  const int q = lane>>4, ln = lane&15;
  const int j = i*16 + ln;
  constexpr int LDK = (ROLE==1) ? 768 : 1024;

  // stage W?ih slice [48][LDK] (rows: gate g, out-col i*16+r16) swizzled into LDS
  for (int u = tid; u < (48*LDK)/8; u += 256) {
    int row = (u*8)/LDK, col = (u*8) - row*LDK;
    int g = row>>4, r16 = row&15;
    short8 v = *(const short8*)(wih + (size_t)(g*1024 + i*16 + r16)*LDK + col);
    *(short8*)(smw + ((row*LDK + col) ^ ((row&7)<<3))) = v;
  }
  // whh slice into registers
  short8 breg[3][8];
  #pragma unroll
  for (int g=0; g<3; ++g) {
    const uint16_t* Bp = whh + (size_t)(g*1024 + j)*1024 + (w*8)*32 + q*8;
    #pragma unroll
    for (int ks=0; ks<8; ++ks) breg[g][ks] = *(const short8*)(Bp + ks*32);
  }
  const float bh0 = bhh[j], bh1 = bhh[1024+j], bh2 = bhh[2048+j];
  const float bi0 = bih[j], bi1 = bih[1024+j], bi2 = bih[2048+j];
  __syncthreads();

  float hold[4] = {0.f,0.f,0.f,0.f};
  f32x4 ga[3];
  if (ROLE != 1) wait_flags(fDep, nDep, 1u);
  fetch_gi<ROLE>(0, X2, MEM, gsrc, smw, w, q, ln, ga);

  for (int t=0; t<TD; ++t) {
    if (t > 0) wait_flags(fOwn, 64, (unsigned)t);   // peers' h[t] visible
    const uint16_t* hp = Hs + (size_t)t*BH;

    f32x4 acc[3][4];
    #pragma unroll
    for (int g=0; g<3; ++g)
      #pragma unroll
      for (int mt=0; mt<4; ++mt) acc[g][mt] = (f32x4){0.f,0.f,0.f,0.f};
    #pragma unroll
    for (int ks=0; ks<8; ++ks) {
      const int k0 = (w*8+ks)*32 + q*8;
      #pragma unroll
      for (int mt=0; mt<4; ++mt) {
        short8 a = *(const short8*)(hp + (size_t)(16*mt+ln)*HH + k0);
        acc[0][mt] = mfma16(a, breg[0][ks], acc[0][mt]);
        acc[1][mt] = mfma16(a, breg[1][ks], acc[1][mt]);
        acc[2][mt] = mfma16(a, breg[2][ks], acc[2][mt]);
      }
    }
    #pragma unroll
    for (int g=0; g<3; ++g)
      #pragma unroll
      for (int mt=0; mt<4; ++mt)
        *(f32x4*)&red[((w*12 + g*4 + mt)*64 + lane)*4] = acc[g][mt];
    __syncthreads();
    f32x4 s[3];
    #pragma unroll
    for (int g=0; g<3; ++g) {
      f32x4 sv = *(const f32x4*)&red[((g*4 + w)*64 + lane)*4];
      #pragma unroll
      for (int kw=1; kw<4; ++kw)
        sv += *(const f32x4*)&red[((kw*12 + g*4 + w)*64 + lane)*4];
      s[g] = sv;
    }

    const uint16_t* gib = (ROLE==2) ? gsrc + (size_t)(t % DRNG)*BH
                        : (ROLE==3) ? gsrc + (size_t)t*BH : nullptr;
    #pragma unroll
    for (int r=0; r<4; ++r) {
      const int b = 16*w + 4*q + r;
      float rg = 1.f/(1.f + __expf(-(ga[0][r] + bi0 + s[0][r] + bh0)));
      float zg = 1.f/(1.f + __expf(-(ga[1][r] + bi1 + s[1][r] + bh1)));
      float nx = ga[2][r] + bi2 + rg*(s[2][r] + bh2);
      float ng = 1.f - 2.f/(1.f + __expf(2.f*nx));   // tanh(nx)
      float hn = (1.f - zg)*ng + zg*hold[r];
      hold[r] = hn;
      Hs[(size_t)(t+1)*BH + (size_t)b*HH + j] = f2bf(hn);
      if (ROLE != 1) {
        float av = bf2f(gib[(size_t)b*HH + j]);       // d2 (L2) / r2 (L3) slice
        rout[((size_t)t*64 + b)*HH + j] = f2bf(hn + av);
      }
    }
    __syncthreads();
    signal_flag(fOwn, i, (unsigned)(t+1));
    if (t+1 < TD) {   // prefetch next step's gi (off the recurrent critical path)
      if (ROLE != 1) wait_flags(fDep, nDep, (unsigned)(t+2));
      fetch_gi<ROLE>(t+1, X2, MEM, gsrc, smw, w, q, ln, ga);
    }
  }
}

// ---------------- attention-projection role ----------------
// 32 blocks, block owns 32 d2-columns. d2[t] = h1[t] @ Wah^T + attpre[t] -> ring.
// Feed-forward only (no self-dependency): trails L1 by its own ~2-3us of work.

__device__ void att_role(int i, const uint16_t* wah, const uint16_t* H1,
    const uint16_t* APRE, uint16_t* D2R,
    unsigned* fA, unsigned* fB, unsigned* fD, uint16_t* smw)
{
  const int tid = threadIdx.x;
  const int w = tid>>6, lane = tid&63;
  const int q = lane>>4, ln = lane&15;
  const int c0 = i*32;
  for (int u = tid; u < (32*1024)/8; u += 256) {
    int row = (u*8)>>10, col = (u*8)&1023;
    short8 v = *(const short8*)(wah + (size_t)(c0+row)*1024 + col);
    *(short8*)(smw + ((row*1024 + col) ^ ((row&7)<<3))) = v;
  }
  __syncthreads();
  const int swz = (ln&7)<<3;
  for (int t=0; t<TD; ++t) {
    wait_flags(fA, 64, (unsigned)(t+1));                       // h1[t] ready
    if (t >= DRNG) wait_flags(fB, 64, (unsigned)(t - DRNG + 1)); // ring backpressure
    const uint16_t* h1t = H1 + (size_t)(t+1)*BH;
    f32x4 dacc[2];
    dacc[0] = (f32x4){0.f,0.f,0.f,0.f}; dacc[1] = dacc[0];
    const uint16_t* a0 = h1t + (size_t)(16*w + ln)*HH + q*8;
    #pragma unroll 8
    for (int ks=0; ks<32; ++ks) {
      short8 a = *(const short8*)(a0 + ks*32);
      #pragma unroll
      for (int jf=0; jf<2; ++jf) {
        short8 b = *(const short8*)(smw + ((((jf*16+ln)*1024) + ks*32 + q*8) ^ swz));
        dacc[jf] = mfma16(a, b, dacc[jf]);
      }
    }
    uint16_t* slot = D2R + (size_t)(t % DRNG)*BH;
    #pragma unroll
    for (int jf=0; jf<2; ++jf)
      #pragma unroll
      for (int r=0; r<4; ++r) {
        int b = 16*w + 4*q + r, col = c0 + 16*jf + ln;
        float v = dacc[jf][r] + bf2f(APRE[((size_t)t*64 + b)*HH + col]);
        slot[(size_t)b*HH + col] = f2bf(v);
      }
    __syncthreads();
    signal_flag(fD, i, (unsigned)(t+1));
  }
}

// ---------------- fused persistent pipeline ----------------
// 224 blocks (<=256 CUs, 1 block/CU due to 144KB LDS -> all co-resident).
// blk 0..63: L1, 64..95: ATT, 96..159: L2, 160..223: L3.
// Dependency DAG is strictly forward: fA -> fD -> fB -> fC (plus per-group barriers).

__global__ __launch_bounds__(256,1)
void k_pipe(const uint16_t* wG1WHH, const uint16_t* wG2WHH, const uint16_t* wG3WHH,
            const uint16_t* wG1WIH, const uint16_t* wG2WIH, const uint16_t* wG3WIH,
            const uint16_t* wATTWH,
            const float* b1ih, const float* b1hh, const float* b2ih, const float* b2hh,
            const float* b3ih, const float* b3hh,
            const uint16_t* X2, const uint16_t* MEM, const uint16_t* APRE,
            uint16_t* H1, uint16_t* H2, uint16_t* H3,
            uint16_t* R2, uint16_t* R3, uint16_t* D2R, unsigned* flags)
{
  __shared__ __align__(16) uint16_t smw[49152];  // 96KB weight slice (swizzled)
  __shared__ __align__(16) float red[12288];     // 48KB cross-wave reduce
  unsigned* fA = flags;             // 64 flags: L1 progress
  unsigned* fD = flags + 64*32;     // 32 flags: ATT progress
  unsigned* fB = flags + 96*32;     // 64 flags: L2 progress
  unsigned* fC = flags + 160*32;    // 64 flags: L3 progress
  const int blk = blockIdx.x;
  if (blk < 64) {
    rec_role<1>(blk, wG1WHH, wG1WIH, b1ih, b1hh, X2, MEM, nullptr,
                H1, nullptr, fA, nullptr, 0, smw, red);
  } else if (blk < 96) {
    att_role(blk-64, wATTWH, H1, APRE, D2R, fA, fB, fD, smw);
  } else if (blk < 160) {
    rec_role<2>(blk-96, wG2WHH, wG2WIH, b2ih, b2hh, nullptr, nullptr, D2R,
                H2, R2, fB, fD, 32, smw, red);
  } else {
    rec_role<3>(blk-160, wG3WHH, wG3WIH, b3ih, b3hh, nullptr, nullptr, R2,
                H3, R3, fC, fB, 64, smw, red);
  }
}

// ---------------- host launch ----------------

extern "C" void kernel_launch(void* const* d_in, const int* in_sizes, int n_in,
                              void* d_out, int out_size, void* d_ws, size_t ws_size,
                              hipStream_t stream)
{
  (void)in_sizes; (void)n_in;
  const float* memorys = (const float*)d_in[0];
  const float* decin   = (const float*)d_in[1];
  const float* pre_w1  = (const float*)d_in[3];
  const float* pre_b1  = (const float*)d_in[4];
  const float* pre_w2  = (const float*)d_in[5];
  const float* pre_b2  = (const float*)d_in[6];
  const float* g1_wih  = (const float*)d_in[7];
  const float* g1_whh  = (const float*)d_in[8];
  const float* g1_bih  = (const float*)d_in[9];
  const float* g1_bhh  = (const float*)d_in[10];
  const float* att_w   = (const float*)d_in[11];
  const float* att_b   = (const float*)d_in[12];
  const float* g2_wih  = (const float*)d_in[13];
  const float* g2_whh  = (const float*)d_in[14];
  const float* g2_bih  = (const float*)d_in[15];
  const float* g2_bhh  = (const float*)d_in[16];
  const float* g3_wih  = (const float*)d_in[17];
  const float* g3_whh  = (const float*)d_in[18];
  const float* g3_bih  = (const float*)d_in[19];
  const float* g3_bhh  = (const float*)d_in[20];
  const float* proj_w  = (const float*)d_in[21];
  const float* proj_b  = (const float*)d_in[22];

  uint16_t* ws = (uint16_t*)d_ws;
  size_t off = 0;
  auto alloc = [&](size_t n){ uint16_t* p = ws + off; off += (n + 127) & ~size_t(127); return p; };

  // weights (bf16)
  uint16_t* wG1WHH = alloc((size_t)3072*1024);
  uint16_t* wG2WHH = alloc((size_t)3072*1024);
  uint16_t* wG3WHH = alloc((size_t)3072*1024);
  uint16_t* wG1WIH = alloc((size_t)3072*768);
  uint16_t* wG2WIH = alloc((size_t)3072*1024);
  uint16_t* wG3WIH = alloc((size_t)3072*1024);
  uint16_t* wATTWH = alloc((size_t)1024*1024);
  uint16_t* wATTWM = alloc((size_t)1024*512);
  uint16_t* wPW1   = alloc((size_t)256*96);
  uint16_t* wPW2   = alloc((size_t)256*256);
  uint16_t* wPROJr = alloc((size_t)160*1024);
  uint16_t* wPROJm = alloc((size_t)160*512);

  float*    PM   = (float*)alloc((size_t)RTOT*160*2);  // f32 mem@projW_m^T + proj_b
  uint16_t* X2   = alloc((size_t)RTOT*256);            // prenet output (persists)
  uint16_t* MEM  = alloc((size_t)RTOT*512);            // pooled memory (persists)
  uint16_t* APRE = alloc((size_t)RTOT*1024);           // attpre -> later overwritten by r3
  uint16_t* H1   = alloc((size_t)(TD+1)*BH);
  uint16_t* H2   = alloc((size_t)(TD+1)*BH);
  uint16_t* H3   = alloc((size_t)(TD+1)*BH);
  uint16_t* R2   = alloc((size_t)RTOT*1024);
  uint16_t* D2R  = alloc((size_t)DRNG*BH);             // d2 ring (64 steps)
  unsigned* flags = (unsigned*)(ws + off); off += 224*32*2 + 256;

  // sub-lifetime aliases (dead before H2/H3 slot-0 zeroing)
  uint16_t* DI96 = H3;   // 64000x96
  uint16_t* X1   = H2;   // 64000x256

  size_t need_bytes = off * 2;
  if (ws_size < need_bytes) {
    float v = 1048576.0f + (float)(ws_size >> 20);
    k_fill<<<dim3((out_size+255)/256), dim3(256), 0, stream>>>((float*)d_out, out_size, v);
    return;
  }

  auto NB = [](long long n){ return dim3((unsigned)((n+255)/256)); };

  // weight conversion / split / pad
  k_cast<<<NB(3072*1024), dim3(256), 0, stream>>>(g1_whh, wG1WHH, 3072, 1024, 0, 1024, 1024);
  k_cast<<<NB(3072*1024), dim3(256), 0, stream>>>(g2_whh, wG2WHH, 3072, 1024, 0, 1024, 1024);
  k_cast<<<NB(3072*1024), dim3(256), 0, stream>>>(g3_whh, wG3WHH, 3072, 1024, 0, 1024, 1024);
  k_cast<<<NB(3072*768),  dim3(256), 0, stream>>>(g1_wih, wG1WIH, 3072, 768, 0, 768, 768);
  k_cast<<<NB(3072*1024), dim3(256), 0, stream>>>(g2_wih, wG2WIH, 3072, 1024, 0, 1024, 1024);
  k_cast<<<NB(3072*1024), dim3(256), 0, stream>>>(g3_wih, wG3WIH, 3072, 1024, 0, 1024, 1024);
  k_cast<<<NB(1024*1024), dim3(256), 0, stream>>>(att_w,  wATTWH, 1024, 1536, 0, 1024, 1024);
  k_cast<<<NB(1024*512),  dim3(256), 0, stream>>>(att_w,  wATTWM, 1024, 1536, 1024, 512, 512);
  k_cast<<<NB(256*96),    dim3(256), 0, stream>>>(pre_w1, wPW1,   256, 80, 0, 80, 96);
  k_cast<<<NB(256*256),   dim3(256), 0, stream>>>(pre_w2, wPW2,   256, 256, 0, 256, 256);
  k_cast<<<NB(160*1024),  dim3(256), 0, stream>>>(proj_w, wPROJr, 160, 1536, 0, 1024, 1024);
  k_cast<<<NB(160*512),   dim3(256), 0, stream>>>(proj_w, wPROJm, 160, 1536, 1024, 512, 512);

  // inputs
  k_di <<<NB((long long)RTOT*96),  dim3(256), 0, stream>>>(decin, DI96);
  k_mem<<<NB((long long)RTOT*EE),  dim3(256), 0, stream>>>(memorys, MEM);

  // prenet
  k_gemm<0,0><<<dim3(2,500), dim3(256), 0, stream>>>(DI96,96,96, nullptr,0,0, wPW1,96, X1,256, pre_b1, nullptr,0, 256, 1);
  k_gemm<0,0><<<dim3(2,500), dim3(256), 0, stream>>>(X1,256,256, nullptr,0,0, wPW2,256, X2,256, pre_b2, nullptr,0, 256, 1);

  // attpre = mem@att_wm^T + att_b ; PM = mem@proj_wm^T + proj_b (f32)
  k_gemm<0,0><<<dim3(8,500), dim3(256), 0, stream>>>(MEM,512,512, nullptr,0,0, wATTWM,512, APRE,1024, att_b, nullptr,0, 1024, 0);
  k_gemm<2,0><<<dim3(2,500), dim3(256), 0, stream>>>(MEM,512,512, nullptr,0,0, wPROJm,512, PM,160, proj_b, nullptr,0, 160, 0);

  // zero initial hidden states + flags (X1/DI96 aliases are dead by now)
  k_zero16<<<NB(BH), dim3(256), 0, stream>>>(H1, BH);
  k_zero16<<<NB(BH), dim3(256), 0, stream>>>(H2, BH);
  k_zero16<<<NB(BH), dim3(256), 0, stream>>>(H3, BH);
  k_zero32<<<dim3(28), dim3(256), 0, stream>>>(flags, 224*32);

  // fused 3-layer pipelined recurrence (single persistent launch)
  k_pipe<<<dim3(224), dim3(256), 0, stream>>>(
      wG1WHH, wG2WHH, wG3WHH, wG1WIH, wG2WIH, wG3WIH, wATTWH,
      g1_bih, g1_bhh, g2_bih, g2_bhh, g3_bih, g3_bhh,
      X2, MEM, APRE, H1, H2, H3, R2, /*R3=*/APRE, D2R, flags);

  // out[b,t,:] = r3@proj_wr^T + PM  (f32, remapped store)
  k_gemm<1,1><<<dim3(2,500), dim3(256), 0, stream>>>(APRE,1024,1024, nullptr,0,0, wPROJr,1024, d_out,160, nullptr, PM,160, 160, 0);
}